// Round 1
// baseline (238.168 us; speedup 1.0000x reference)
//
#include <hip/hip_runtime.h>
#include <math.h>

#define NROWS (1024u * 4096u)      // 2^22 rows
#define BLOCKS 2048
#define TPB 256
#define R 8                        // NROWS / (BLOCKS*TPB), exact
#define NW (TPB / 64)              // waves per block

__global__ __launch_bounds__(TPB) void penalty_fused(
        const float* __restrict__ x,
        const float* __restrict__ min_,
        const float* __restrict__ scale_,
        unsigned int* __restrict__ part,   // BLOCKS*4 uints
        unsigned int* __restrict__ cnt,    // 1 uint, zeroed by memset node
        float* __restrict__ out) {
    const float min2 = min_[2], min3 = min_[3];
    const float sc2  = scale_[2], sc3 = scale_[3];

    const int tid  = threadIdx.x;
    const int lane = tid & 63;
    const int wave = tid >> 6;
    const unsigned T = BLOCKS * TPB;                    // 2^19
    const unsigned t = blockIdx.x * TPB + tid;          // thread's first row

    // ---- phase 1: 8 independent loads in flight ----
    float2 v[R];
    #pragma unroll
    for (int r = 0; r < R; ++r) {
        v[r] = *(const float2*)(x + 8u * (t + (unsigned)r * T) + 2u);
    }

    // ---- phase 2: per-row predicates (keep exact IEEE division:
    //      reciprocal-multiply risks 1-ulp flips of the a>22 compare) ----
    float a[R];
    unsigned c1 = 0, c2 = 0, c4 = 0;
    #pragma unroll
    for (int r = 0; r < R; ++r) {
        const float d = (v[r].x - min2) / sc2;
        a[r] = (v[r].y - min3) / sc3;
        c1 += !(d >= 0.0f && d <= 252.0f);
        c2 += (a[r] < 0.0f) || (a[r] > 22.0f);
        c4 += (a[r] != 22.0f);
    }

    // ---- cross-wave handoff: each wave's lane 0 publishes its a[] ----
    __shared__ float sA[NW][R];
    if (lane == 0) {
        #pragma unroll
        for (int r = 0; r < R; ++r) sA[wave][r] = a[r];
    }
    __syncthreads();

    // tid==255: neighbor rows live in the next block -> 8 boundary loads
    float abound[R];
    if (tid == TPB - 1) {
        #pragma unroll
        for (int r = 0; r < R; ++r) {
            const unsigned j = t + (unsigned)r * T + 1u;   // == NROWS only for last row
            abound[r] = (j < NROWS) ? (x[8u * j + 3u] - min3) / sc3 : 0.0f;
        }
    }

    // ---- transition penalty ----
    unsigned c3 = 0;
    #pragma unroll
    for (int r = 0; r < R; ++r) {
        float an = __shfl_down(a[r], 1);
        if (lane == 63) an = (wave < NW - 1) ? sA[wave + 1][r] : abound[r];
        const unsigned i = t + (unsigned)r * T;
        const bool cond = (fmodf(a[r], 2.0f) == 0.0f) && (a[r] < 20.0f)
                          && (i + 1u < NROWS);
        const bool invalid = (an != a[r] + 1.0f) && (an != 22.0f);
        c3 += (cond && invalid);
    }

    // ---- block reduction, no atomics ----
    for (int off = 32; off > 0; off >>= 1) {
        c1 += __shfl_down(c1, off);
        c2 += __shfl_down(c2, off);
        c3 += __shfl_down(c3, off);
        c4 += __shfl_down(c4, off);
    }
    __shared__ unsigned int s[NW][4];
    __shared__ int isLast;
    if (lane == 0) { s[wave][0] = c1; s[wave][1] = c2; s[wave][2] = c3; s[wave][3] = c4; }
    __syncthreads();

    if (tid == 0) {
        unsigned t1 = 0, t2 = 0, t3 = 0, t4 = 0;
        #pragma unroll
        for (int w = 0; w < NW; ++w) {
            t1 += s[w][0]; t2 += s[w][1]; t3 += s[w][2]; t4 += s[w][3];
        }
        unsigned int* p = part + 4u * blockIdx.x;
        p[0] = t1; p[1] = t2; p[2] = t3; p[3] = t4;
        __threadfence();                               // release partials (device scope)
        const unsigned done = atomicAdd(cnt, 1u);      // device-scope by default
        isLast = (done == BLOCKS - 1);
    }
    __syncthreads();

    // ---- last-arriving block reduces all partials and writes out ----
    if (isLast) {
        __threadfence();                               // acquire
        unsigned g1 = 0, g2 = 0, g3 = 0, g4 = 0;
        // volatile: bypass L1/L2 caching of other XCDs' partials
        volatile const unsigned int* vp = part;
        for (int b = tid; b < BLOCKS; b += TPB) {
            g1 += vp[4 * b + 0];
            g2 += vp[4 * b + 1];
            g3 += vp[4 * b + 2];
            g4 += vp[4 * b + 3];
        }
        for (int off = 32; off > 0; off >>= 1) {
            g1 += __shfl_down(g1, off);
            g2 += __shfl_down(g2, off);
            g3 += __shfl_down(g3, off);
            g4 += __shfl_down(g4, off);
        }
        if (lane == 0) { s[wave][0] = g1; s[wave][1] = g2; s[wave][2] = g3; s[wave][3] = g4; }
        __syncthreads();
        if (tid == 0) {
            unsigned t1 = 0, t2 = 0, t3 = 0, t4 = 0;
            #pragma unroll
            for (int w = 0; w < NW; ++w) {
                t1 += s[w][0]; t2 += s[w][1]; t3 += s[w][2]; t4 += s[w][3];
            }
            out[0] = (float)t1 + (float)t2 + (float)t3
                   + fabsf((float)t4 - 58.0f);
        }
    }
}

extern "C" void kernel_launch(void* const* d_in, const int* in_sizes, int n_in,
                              void* d_out, int out_size, void* d_ws, size_t ws_size,
                              hipStream_t stream) {
    const float* x  = (const float*)d_in[0];
    const float* mn = (const float*)d_in[1];
    const float* sc = (const float*)d_in[2];
    unsigned int* part = (unsigned int*)d_ws;              // 32 KB
    unsigned int* cnt  = part + 4u * BLOCKS;               // 1 uint after partials
    float* out = (float*)d_out;

    // zero the arrival counter each replay (graph-capturable memset node)
    hipMemsetAsync(cnt, 0, sizeof(unsigned int), stream);
    penalty_fused<<<BLOCKS, TPB, 0, stream>>>(x, mn, sc, part, cnt, out);
}

// Round 2
// 199.392 us; speedup vs baseline: 1.1945x; 1.1945x over previous
//
#include <hip/hip_runtime.h>
#include <math.h>

#define NROWS (1024u * 4096u)      // 2^22 rows
#define BLOCKS 2048
#define TPB 256
#define R 8                        // rows per thread
#define RPB (TPB * R)              // 2048 contiguous rows per block (64 KB of x)
#define NW (TPB / 64)              // waves per block

// Block b owns rows [b*RPB, (b+1)*RPB). Thread tid handles rows
// base + r*TPB + tid for r = 0..7  -> per-instruction coalescing unchanged
// (lanes stride 32 B), but all 8 per-thread streams stay inside the block's
// contiguous 64 KB chunk instead of spanning 128 MB at 16 MB stride.
__global__ __launch_bounds__(TPB) void penalty_main(
        const float* __restrict__ x,
        const float* __restrict__ min_,
        const float* __restrict__ scale_,
        unsigned int* __restrict__ part) {
    const float min2 = min_[2], min3 = min_[3];
    const float sc2  = scale_[2], sc3 = scale_[3];

    const int tid  = threadIdx.x;
    const int lane = tid & 63;
    const int wave = tid >> 6;
    const unsigned base = blockIdx.x * RPB;

    // boundary row: first row of the NEXT block (only tid 255 needs it).
    // Issued first so it overlaps the main loads.
    float abound = 0.0f;
    if (tid == TPB - 1) {
        const unsigned j = base + RPB;                 // == NROWS only for last block
        if (j < NROWS) abound = (x[8u * j + 3u] - min3) / sc3;
    }

    // ---- phase 1: 8 independent loads in flight ----
    float2 v[R];
    #pragma unroll
    for (int r = 0; r < R; ++r) {
        const unsigned i = base + (unsigned)r * TPB + (unsigned)tid;
        v[r] = *(const float2*)(x + 8u * i + 2u);
    }

    // ---- phase 2: per-row predicates (exact IEEE division kept:
    //      reciprocal-multiply risks 1-ulp flips of the a>22 compare) ----
    float a[R];
    unsigned c1 = 0, c2 = 0, c4 = 0;
    #pragma unroll
    for (int r = 0; r < R; ++r) {
        const float d = (v[r].x - min2) / sc2;
        a[r] = (v[r].y - min3) / sc3;
        c1 += !(d >= 0.0f && d <= 252.0f);
        c2 += (a[r] < 0.0f) || (a[r] > 22.0f);
        c4 += (a[r] != 22.0f);
    }

    // ---- cross-wave handoff: each wave's lane 0 publishes its a[] ----
    // Row numbering: (r, tid) -> base + r*256 + tid, so the successor of
    //   (r, lane 63 of wave w)  is (r, lane 0 of wave w+1)      [w < 3]
    //   (r, tid 255)            is (r+1, lane 0 of wave 0)      [r < 7]
    //   (7, tid 255)            is the next block's first row -> abound
    __shared__ float sA[NW][R];
    if (lane == 0) {
        #pragma unroll
        for (int r = 0; r < R; ++r) sA[wave][r] = a[r];
    }
    __syncthreads();

    // ---- transition penalty ----
    unsigned c3 = 0;
    #pragma unroll
    for (int r = 0; r < R; ++r) {
        float an = __shfl_down(a[r], 1);
        if (lane == 63) {
            if (wave < NW - 1)    an = sA[wave + 1][r];
            else if (r < R - 1)   an = sA[0][r + 1];
            else                  an = abound;
        }
        const unsigned i = base + (unsigned)r * TPB + (unsigned)tid;
        const bool cond = (fmodf(a[r], 2.0f) == 0.0f) && (a[r] < 20.0f)
                          && (i + 1u < NROWS);
        const bool invalid = (an != a[r] + 1.0f) && (an != 22.0f);
        c3 += (cond && invalid);
    }

    // ---- block reduction, no atomics, no fences ----
    for (int off = 32; off > 0; off >>= 1) {
        c1 += __shfl_down(c1, off);
        c2 += __shfl_down(c2, off);
        c3 += __shfl_down(c3, off);
        c4 += __shfl_down(c4, off);
    }
    __shared__ unsigned int s[NW][4];
    if (lane == 0) { s[wave][0] = c1; s[wave][1] = c2; s[wave][2] = c3; s[wave][3] = c4; }
    __syncthreads();
    if (tid == 0) {
        unsigned t1 = 0, t2 = 0, t3 = 0, t4 = 0;
        #pragma unroll
        for (int w = 0; w < NW; ++w) {
            t1 += s[w][0]; t2 += s[w][1]; t3 += s[w][2]; t4 += s[w][3];
        }
        unsigned int* p = part + 4u * blockIdx.x;
        p[0] = t1; p[1] = t2; p[2] = t3; p[3] = t4;
    }
}

__global__ __launch_bounds__(TPB) void finalize(
        const unsigned int* __restrict__ part, float* __restrict__ out) {
    const int tid = threadIdx.x;
    unsigned c1 = 0, c2 = 0, c3 = 0, c4 = 0;
    for (int b = tid; b < BLOCKS; b += TPB) {
        const unsigned int* p = part + 4 * b;
        c1 += p[0]; c2 += p[1]; c3 += p[2]; c4 += p[3];
    }
    for (int off = 32; off > 0; off >>= 1) {
        c1 += __shfl_down(c1, off);
        c2 += __shfl_down(c2, off);
        c3 += __shfl_down(c3, off);
        c4 += __shfl_down(c4, off);
    }
    __shared__ unsigned int s[NW][4];
    const int lane = tid & 63, wave = tid >> 6;
    if (lane == 0) { s[wave][0] = c1; s[wave][1] = c2; s[wave][2] = c3; s[wave][3] = c4; }
    __syncthreads();
    if (tid == 0) {
        unsigned t1 = 0, t2 = 0, t3 = 0, t4 = 0;
        #pragma unroll
        for (int w = 0; w < NW; ++w) {
            t1 += s[w][0]; t2 += s[w][1]; t3 += s[w][2]; t4 += s[w][3];
        }
        out[0] = (float)t1 + (float)t2 + (float)t3
               + fabsf((float)t4 - 58.0f);
    }
}

extern "C" void kernel_launch(void* const* d_in, const int* in_sizes, int n_in,
                              void* d_out, int out_size, void* d_ws, size_t ws_size,
                              hipStream_t stream) {
    const float* x  = (const float*)d_in[0];
    const float* mn = (const float*)d_in[1];
    const float* sc = (const float*)d_in[2];
    unsigned int* part = (unsigned int*)d_ws;      // BLOCKS*4 uints = 32 KB
    float* out = (float*)d_out;

    penalty_main<<<BLOCKS, TPB, 0, stream>>>(x, mn, sc, part);
    finalize<<<1, TPB, 0, stream>>>(part, out);
}